// Round 1
// baseline (381.438 us; speedup 1.0000x reference)
//
#include <hip/hip_runtime.h>
#include <hip/hip_bf16.h>

// Problem constants
#define TT 512   // T
#define BB 128   // B
#define HH 512   // H
#define NFC 128  // NF
// FS = 5

typedef short v8s __attribute__((ext_vector_type(8)));
typedef float v4f __attribute__((ext_vector_type(4)));

__device__ __forceinline__ unsigned short f2bf(float x) {
    unsigned u = __float_as_uint(x);
    unsigned r = (u + 0x7fffu + ((u >> 16) & 1u)) >> 16;
    return (unsigned short)r;
}

// ---------------------------------------------------------------------------
// Kernel 0: fused prep + gather.  (unchanged)
// blocks [0,8192): gather X_all, [n][h] bf16, n=b*512+l; skip unread tiles.
// blocks [8192,12288): build stacked weight Wg, bf16, M=2048 x K=512.
// blocks [12288,12608): zero pools.
// block 12608: collapse fc2∘fc1 into v[640] + c.
// block 12609: parallel worklist of active (b,tt) items (unordered).
// ---------------------------------------------------------------------------
__global__ void prep_all(const float* __restrict__ enc, const int* __restrict__ lengths,
                         unsigned short* __restrict__ Xg,
                         const float* __restrict__ w1, const float* __restrict__ w2,
                         const float* __restrict__ w3, const float* __restrict__ w4,
                         const float* __restrict__ w5, unsigned short* __restrict__ Wg,
                         float* __restrict__ pools,
                         const float* __restrict__ fc1w, const float* __restrict__ fc1b,
                         const float* __restrict__ fc2w, const float* __restrict__ fc2b,
                         float* __restrict__ v, int* __restrict__ wl) {
    int blk = blockIdx.x;
    int tid = threadIdx.x;
    if (blk < 8192) {
        __shared__ float tile[64 * 65];
        int b = blk >> 6;
        int lc = (blk >> 3) & 7;
        int hc = blk & 7;
        int L = lengths[b];
        int Leff = L > 5 ? L : 5;
        int l0 = lc * 64, h0 = hc * 64;
        if (l0 >= Leff + 127) return;     // never read by any active tile
        int lx = tid & 63;
        int hq = tid >> 6;                // 0..3
        #pragma unroll
        for (int r = 0; r < 16; ++r) {
            int hl = hq * 16 + r;         // local h
            int l = l0 + lx;
            float val = 0.f;
            if (l < L) {
                int i = (h0 + hl) * L + l;
                val = enc[(i >> 9) * (BB * HH) + b * HH + (i & 511)];
            }
            tile[hl * 65 + lx] = val;
        }
        __syncthreads();
        int hg = tid & 15;                // h quad within tile (4 bf16 = 8B)
        #pragma unroll
        for (int r = 0; r < 4; ++r) {
            int lloc = (tid >> 4) + r * 16;
            int n = b * 512 + l0 + lloc;
            ushort4 pk;
            pk.x = f2bf(tile[(hg * 4 + 0) * 65 + lloc]);
            pk.y = f2bf(tile[(hg * 4 + 1) * 65 + lloc]);
            pk.z = f2bf(tile[(hg * 4 + 2) * 65 + lloc]);
            pk.w = f2bf(tile[(hg * 4 + 3) * 65 + lloc]);
            *(ushort4*)&Xg[n * 512 + h0 + hg * 4] = pk;
        }
    } else if (blk < 12288) {
        int idx = (blk - 8192) * 256 + tid;   // 2048*512 = 1,048,576
        int s = idx >> 9, h = idx & 511;
        int f = s >> 4, sl = s & 15;
        float val = 0.f;
        if (sl < 15) {
            int w, j;
            if (sl < 1)       { w = 1; j = sl; }
            else if (sl < 3)  { w = 2; j = sl - 1; }
            else if (sl < 6)  { w = 3; j = sl - 3; }
            else if (sl < 10) { w = 4; j = sl - 6; }
            else              { w = 5; j = sl - 10; }
            const float* wp = (w == 1) ? w1 : (w == 2) ? w2 : (w == 3) ? w3 : (w == 4) ? w4 : w5;
            val = wp[f * (HH * w) + h * w + j];  // conv_w{w}[f,0,h,j]
        }
        Wg[idx] = f2bf(val);
    } else if (blk < 12608) {
        int i = (blk - 12288) * 256 + tid;
        if (i < BB * 5 * NFC) pools[i] = 0.f;
    } else if (blk == 12608) {
        for (int k = tid; k < 640; k += 256) {
            float s = 0.f;
            for (int o = 0; o < 100; ++o) s += fc2w[o] * fc1w[o * 640 + k];
            v[k] = s;
        }
        if (tid == 0) {
            float c = fc2b[0];
            for (int o = 0; o < 100; ++o) c += fc2w[o] * fc1b[o];
            v[640] = c;
        }
    } else {
        __shared__ int cnt;
        if (tid == 0) cnt = 0;
        __syncthreads();
        for (int it = tid; it < 640; it += 256) {
            int b = it / 5, tt = it % 5;
            int L = lengths[b];
            int Leff = L > 5 ? L : 5;
            int n0 = tt * 124 - ((tt >> 2) * 112);   // {0,124,248,372,384}
            if (n0 < Leff) {
                int pos = atomicAdd(&cnt, 1);
                wl[pos] = (b << 3) | tt;
            }
        }
        __syncthreads();
        if (tid == 0) wl[640] = cnt;
    }
}

// ---------------------------------------------------------------------------
// Kernel 1: main fused GEMM + epilogue.
// r12 change: DEPTH-2 COUNTED-vmcnt PIPELINE (T4). The r11 loop ended every
// kt with __syncthreads(), whose compiler lowering drains vmcnt(0) — i.e.
// waits on the stage(kt+1) loads issued only ~300cy earlier. With MfmaUtil
// 27.6 / VALUBusy 28.5 / HBM 15% nothing was saturated: pure latency stall.
// New loop: 3 LDS buffers; iter kt issues stage(kt+2) and waits vmcnt(8),
// which by FIFO waitcnt semantics (m135) waits exactly for stage(kt) —
// issued TWO iterations (~800+cy) ago, covering even HBM-miss latency.
// Two raw s_barriers per kt:
//   B1 after vmcnt         -> buf[kt%3] visible to all waves
//   B2 after ds_read+lgkm0 -> all waves done reading buf[kt%3] before the
//                             next iteration re-stages that slot (WAR)
// sched_barrier(0) after lgkm0 per rule #18; setprio(1) around MFMA (T5).
// vmcnt tail: kt=14 -> vmcnt(4), kt=15 -> vmcnt(0).
// LDS 33->48 KB: occupancy 4->3 blocks/CU; pipeline depth replaces the TLP.
// Grid stays (16, 640) mt-fast for L2 reuse of the per-item B slab.
// All global traffic via global_load_lds; swizzle unchanged: physical 16B
// chunk p = q ^ ((row>>1)&3), staging permutes the GLOBAL address (m104).
// ---------------------------------------------------------------------------
__global__ __launch_bounds__(256, 3)
void conv_gemm(const unsigned short* __restrict__ Wg, const unsigned short* __restrict__ Xg,
               const int* __restrict__ lengths, const int* __restrict__ wl,
               const float* __restrict__ cb1, const float* __restrict__ cb2,
               const float* __restrict__ cb3, const float* __restrict__ cb4,
               const float* __restrict__ cb5,
               float* __restrict__ pools) {
    __shared__ __align__(16) char smem[49152];               // 3x(8K A + 8K B)
    unsigned short* ldsA = (unsigned short*)smem;            // 3 x 4096 ushorts
    unsigned short* ldsB = ldsA + 12288;                     // 3 x 4096 ushorts
    float* Gs = (float*)smem;                                // 64*129 floats (epilogue, 33024B)

    int cnt = wl[640];
    int wk = blockIdx.y;
    if (wk >= cnt) return;
    int item = wl[wk];
    int b = item >> 3, tt = item & 7;
    int mt = blockIdx.x;
    int n0 = tt * 124 - ((tt >> 2) * 112);   // {0,124,248,372,384}
    int L = lengths[b];
    int Leff = L > 5 ? L : 5;

    int tid = threadIdx.x;
    int wid = tid >> 6, lane = tid & 63;
    int wm = wid >> 1, wn = wid & 1;
    int llo = lane & 15, quad = lane >> 4;
    int psw = quad ^ ((llo >> 1) & 3);   // swizzled physical chunk for frag reads

    int m0 = mt * 128;
    int nb0 = b * 512 + n0;

    v4f acc[4][4];
    #pragma unroll
    for (int i = 0; i < 4; ++i)
        #pragma unroll
        for (int j = 0; j < 4; ++j) acc[i][j] = v4f{0.f, 0.f, 0.f, 0.f};

    // staging: wave wid covers rows [wid*32, wid*32+32) in 2 insts of 16 rows
    int srow = lane >> 2;                           // 0..15
    int gchunk = (lane & 3) ^ ((lane >> 3) & 3);    // global chunk for physical slot lane&3
    const unsigned short* gA = Wg + (m0 + wid * 32 + srow) * 512 + gchunk * 8;
    const unsigned short* gB = Xg + (nb0 + wid * 32 + srow) * 512 + gchunk * 8;
    int sdst = (wid * 32) * 32;   // ushort offset of this wave's staging rows

    // prologue: stage k-tiles 0,1 into buffers 0,1 (8 insts/thread in flight)
    #pragma unroll
    for (int p = 0; p < 2; ++p) {
        #pragma unroll
        for (int q = 0; q < 2; ++q) {
            __builtin_amdgcn_global_load_lds(
                (const __attribute__((address_space(1))) unsigned int*)(gA + q * (16 * 512) + p * 32),
                (__attribute__((address_space(3))) unsigned int*)&ldsA[p * 4096 + sdst + q * 512],
                16, 0, 0);
            __builtin_amdgcn_global_load_lds(
                (const __attribute__((address_space(1))) unsigned int*)(gB + q * (16 * 512) + p * 32),
                (__attribute__((address_space(3))) unsigned int*)&ldsB[p * 4096 + sdst + q * 512],
                16, 0, 0);
        }
    }

    int bcur = 0;
    #pragma unroll 1
    for (int kt = 0; kt < 16; ++kt) {
        // issue stage(kt+2) into the third buffer, then wait ONLY for
        // stage(kt): vmcnt(8) leaves the 8 insts of stages kt+1,kt+2 in flight.
        if (kt < 14) {
            int bnx = bcur + 2; if (bnx >= 3) bnx -= 3;
            int ko = (kt + 2) * 32;
            #pragma unroll
            for (int q = 0; q < 2; ++q) {
                __builtin_amdgcn_global_load_lds(
                    (const __attribute__((address_space(1))) unsigned int*)(gA + q * (16 * 512) + ko),
                    (__attribute__((address_space(3))) unsigned int*)&ldsA[bnx * 4096 + sdst + q * 512],
                    16, 0, 0);
                __builtin_amdgcn_global_load_lds(
                    (const __attribute__((address_space(1))) unsigned int*)(gB + q * (16 * 512) + ko),
                    (__attribute__((address_space(3))) unsigned int*)&ldsB[bnx * 4096 + sdst + q * 512],
                    16, 0, 0);
            }
            asm volatile("s_waitcnt vmcnt(8)" ::: "memory");
        } else if (kt == 14) {
            asm volatile("s_waitcnt vmcnt(4)" ::: "memory");
        } else {
            asm volatile("s_waitcnt vmcnt(0)" ::: "memory");
        }
        __builtin_amdgcn_s_barrier();        // buf[bcur] fully staged, all waves

        int boff = bcur * 4096;
        v8s Af[4], Bf[4];
        #pragma unroll
        for (int mi = 0; mi < 4; ++mi)
            Af[mi] = *(const v8s*)&ldsA[boff + (wm * 64 + mi * 16 + llo) * 32 + psw * 8];
        #pragma unroll
        for (int ni = 0; ni < 4; ++ni)
            Bf[ni] = *(const v8s*)&ldsB[boff + (wn * 64 + ni * 16 + llo) * 32 + psw * 8];
        asm volatile("s_waitcnt lgkmcnt(0)" ::: "memory");
        __builtin_amdgcn_sched_barrier(0);   // rule #18: pin MFMA below lgkm wait
        __builtin_amdgcn_s_barrier();        // all waves done reading buf[bcur]
                                             // -> next iter may re-stage this slot

        __builtin_amdgcn_s_setprio(1);
        #pragma unroll
        for (int mi = 0; mi < 4; ++mi)
            #pragma unroll
            for (int ni = 0; ni < 4; ++ni)
                acc[mi][ni] = __builtin_amdgcn_mfma_f32_16x16x32_bf16(Af[mi], Bf[ni], acc[mi][ni], 0, 0, 0);
        __builtin_amdgcn_s_setprio(0);

        bcur += 1; if (bcur >= 3) bcur -= 3;
    }

    // ---- epilogue: 2 phases of 64 rows (4 filter groups each) ----
    const int basew[6] = {0, 0, 1, 3, 6, 10};

    #pragma unroll
    for (int phase = 0; phase < 2; ++phase) {
        if (wm == phase) {
            // C/D layout: col = lane&15, row = quad*4 + reg  [verified m89/m91]
            #pragma unroll
            for (int mi = 0; mi < 4; ++mi)
                #pragma unroll
                for (int ni = 0; ni < 4; ++ni)
                    #pragma unroll
                    for (int r = 0; r < 4; ++r)
                        Gs[(mi * 16 + quad * 4 + r) * 129 + wn * 64 + ni * 16 + llo] = acc[mi][ni][r];
        }
        __syncthreads();
        // pooling: wave wid handles filter group fl = wid of this phase
        {
            int fl = wid;
            int f = mt * 8 + phase * 4 + fl;
            #pragma unroll
            for (int w = 1; w <= 5; ++w) {
                float bias = (w == 1 ? cb1 : w == 2 ? cb2 : w == 3 ? cb3 : w == 4 ? cb4 : cb5)[f];
                int limv = Leff - w + 1 - n0;          // tile-local validity bound
                float vmax = -1.f;
                #pragma unroll
                for (int half = 0; half < 2; ++half) {
                    int t = half * 64 + lane;
                    if (t <= 128 - w && t < limv) {
                        float s = 0.f;
                        #pragma unroll
                        for (int j = 0; j < w; ++j)
                            s += Gs[(fl * 16 + basew[w] + j) * 129 + t + j];
                        s += bias;
                        s = fmaxf(s, 0.f);
                        vmax = fmaxf(vmax, s);
                    }
                }
                #pragma unroll
                for (int off = 32; off >= 1; off >>= 1)
                    vmax = fmaxf(vmax, __shfl_xor(vmax, off));
                if (lane == 0 && vmax >= 0.f)
                    atomicMax((int*)&pools[(b * 5 + (w - 1)) * NFC + f], __float_as_int(vmax));
            }
        }
        __syncthreads();
    }
}

// ---------------------------------------------------------------------------
// Kernel 2: per-batch dot(feat, v) + c -> sigmoid.  (unchanged)
// ---------------------------------------------------------------------------
__global__ void head(const float* __restrict__ pools, const float* __restrict__ v,
                     float* __restrict__ out) {
    int b = blockIdx.x;
    int tid = threadIdx.x;
    float s = 0.f;
    for (int k = tid; k < 640; k += 256) s += pools[b * 640 + k] * v[k];
    __shared__ float red[256];
    red[tid] = s;
    __syncthreads();
    for (int st = 128; st; st >>= 1) {
        if (tid < st) red[tid] += red[tid + st];
        __syncthreads();
    }
    if (tid == 0) out[b] = 1.f / (1.f + expf(-(red[0] + v[640])));
}

// ---------------------------------------------------------------------------
extern "C" void kernel_launch(void* const* d_in, const int* in_sizes, int n_in,
                              void* d_out, int out_size, void* d_ws, size_t ws_size,
                              hipStream_t stream) {
    const float* enc  = (const float*)d_in[0];
    const int* lens   = (const int*)d_in[1];
    const float* w1   = (const float*)d_in[2];
    const float* b1   = (const float*)d_in[3];
    const float* w2   = (const float*)d_in[4];
    const float* b2   = (const float*)d_in[5];
    const float* w3   = (const float*)d_in[6];
    const float* b3   = (const float*)d_in[7];
    const float* w4   = (const float*)d_in[8];
    const float* b4   = (const float*)d_in[9];
    const float* w5   = (const float*)d_in[10];
    const float* b5   = (const float*)d_in[11];
    const float* fc1w = (const float*)d_in[12];
    const float* fc1b = (const float*)d_in[13];
    const float* fc2w = (const float*)d_in[14];
    const float* fc2b = (const float*)d_in[15];
    float* out = (float*)d_out;

    // workspace layout
    unsigned short* Xg = (unsigned short*)d_ws;          // 33,554,432 ushorts (64 MB)
    unsigned short* Wg = Xg + 33554432;                  // 1,048,576 ushorts (2 MB)
    float* pools  = (float*)(Wg + 1048576);              // 81,920 floats
    float* vbuf   = pools + 81920;                       // 641 floats
    int* wlist    = (int*)(vbuf + 641);                  // 641 ints

    prep_all<<<12610, 256, 0, stream>>>(enc, lens, Xg, w1, w2, w3, w4, w5, Wg, pools,
                                        fc1w, fc1b, fc2w, fc2b, vbuf, wlist);
    conv_gemm<<<dim3(16, 640), 256, 0, stream>>>(Wg, Xg, lens, wlist, b1, b2, b3, b4, b5, pools);
    head<<<128, 256, 0, stream>>>(pools, vbuf, out);
}

// Round 2
// 359.637 us; speedup vs baseline: 1.0606x; 1.0606x over previous
//
#include <hip/hip_runtime.h>
#include <hip/hip_bf16.h>

// Problem constants
#define TT 512   // T
#define BB 128   // B
#define HH 512   // H
#define NFC 128  // NF
// FS = 5

typedef short v8s __attribute__((ext_vector_type(8)));
typedef float v4f __attribute__((ext_vector_type(4)));

__device__ __forceinline__ unsigned short f2bf(float x) {
    unsigned u = __float_as_uint(x);
    unsigned r = (u + 0x7fffu + ((u >> 16) & 1u)) >> 16;
    return (unsigned short)r;
}

// ---------------------------------------------------------------------------
// Kernel 0: fused prep + gather.
// blocks [0,8192): gather X_all, [n][h] bf16, n=b*512+l; skip unread tiles.
// blocks [8192,12288): build Wg2: weight matrix PRE-SWIZZLED into per-lane
//   MFMA A-fragment order:  o = ((((mt*2+wm)*16 + kt)*4 + mi)*64 + lane)*8 + j
//   holds A[row = mt*128+wm*64+mi*16+(lane&15)][k = kt*32+(lane>>4)*8+j].
//   conv_gemm then loads A-frags with coalesced global_load_dwordx4 (16B/lane)
//   straight from L2 (Wg2 = 2MB, resident per-XCD) — A never touches LDS.
// blocks [12288,12608): zero pools.
// block 12608: collapse fc2∘fc1 into v[640] + c.
// block 12609: parallel worklist of active (b,tt) items (unordered).
// ---------------------------------------------------------------------------
__global__ void prep_all(const float* __restrict__ enc, const int* __restrict__ lengths,
                         unsigned short* __restrict__ Xg,
                         const float* __restrict__ w1, const float* __restrict__ w2,
                         const float* __restrict__ w3, const float* __restrict__ w4,
                         const float* __restrict__ w5, unsigned short* __restrict__ Wg,
                         float* __restrict__ pools,
                         const float* __restrict__ fc1w, const float* __restrict__ fc1b,
                         const float* __restrict__ fc2w, const float* __restrict__ fc2b,
                         float* __restrict__ v, int* __restrict__ wl) {
    int blk = blockIdx.x;
    int tid = threadIdx.x;
    if (blk < 8192) {
        __shared__ float tile[64 * 65];
        int b = blk >> 6;
        int lc = (blk >> 3) & 7;
        int hc = blk & 7;
        int L = lengths[b];
        int Leff = L > 5 ? L : 5;
        int l0 = lc * 64, h0 = hc * 64;
        if (l0 >= Leff + 127) return;     // never read by any active tile
        int lx = tid & 63;
        int hq = tid >> 6;                // 0..3
        #pragma unroll
        for (int r = 0; r < 16; ++r) {
            int hl = hq * 16 + r;         // local h
            int l = l0 + lx;
            float val = 0.f;
            if (l < L) {
                int i = (h0 + hl) * L + l;
                val = enc[(i >> 9) * (BB * HH) + b * HH + (i & 511)];
            }
            tile[hl * 65 + lx] = val;
        }
        __syncthreads();
        int hg = tid & 15;                // h quad within tile (4 bf16 = 8B)
        #pragma unroll
        for (int r = 0; r < 4; ++r) {
            int lloc = (tid >> 4) + r * 16;
            int n = b * 512 + l0 + lloc;
            ushort4 pk;
            pk.x = f2bf(tile[(hg * 4 + 0) * 65 + lloc]);
            pk.y = f2bf(tile[(hg * 4 + 1) * 65 + lloc]);
            pk.z = f2bf(tile[(hg * 4 + 2) * 65 + lloc]);
            pk.w = f2bf(tile[(hg * 4 + 3) * 65 + lloc]);
            *(ushort4*)&Xg[n * 512 + h0 + hg * 4] = pk;
        }
    } else if (blk < 12288) {
        int o = (blk - 8192) * 256 + tid;     // [0, 1,048,576)
        // fragment-order decomposition
        int j   = o & 7;
        int ln  = (o >> 3) & 63;
        int mi  = (o >> 9) & 3;
        int kt  = (o >> 11) & 15;
        int wmm = (o >> 15) & 1;
        int mtt = o >> 16;
        int row = mtt * 128 + wmm * 64 + mi * 16 + (ln & 15);   // 0..2047
        int k   = kt * 32 + (ln >> 4) * 8 + j;                  // 0..511
        int f = row >> 4, sl = row & 15;
        float val = 0.f;
        if (sl < 15) {
            int w, jj;
            if (sl < 1)       { w = 1; jj = sl; }
            else if (sl < 3)  { w = 2; jj = sl - 1; }
            else if (sl < 6)  { w = 3; jj = sl - 3; }
            else if (sl < 10) { w = 4; jj = sl - 6; }
            else              { w = 5; jj = sl - 10; }
            const float* wp = (w == 1) ? w1 : (w == 2) ? w2 : (w == 3) ? w3 : (w == 4) ? w4 : w5;
            val = wp[f * (HH * w) + k * w + jj];  // conv_w{w}[f,0,h=k,jj]
        }
        Wg[o] = f2bf(val);
    } else if (blk < 12608) {
        int i = (blk - 12288) * 256 + tid;
        if (i < BB * 5 * NFC) pools[i] = 0.f;
    } else if (blk == 12608) {
        for (int k = tid; k < 640; k += 256) {
            float s = 0.f;
            for (int o = 0; o < 100; ++o) s += fc2w[o] * fc1w[o * 640 + k];
            v[k] = s;
        }
        if (tid == 0) {
            float c = fc2b[0];
            for (int o = 0; o < 100; ++o) c += fc2w[o] * fc1b[o];
            v[640] = c;
        }
    } else {
        __shared__ int cnt;
        if (tid == 0) cnt = 0;
        __syncthreads();
        for (int it = tid; it < 640; it += 256) {
            int b = it / 5, tt = it % 5;
            int L = lengths[b];
            int Leff = L > 5 ? L : 5;
            int n0 = tt * 124 - ((tt >> 2) * 112);   // {0,124,248,372,384}
            if (n0 < Leff) {
                int pos = atomicAdd(&cnt, 1);
                wl[pos] = (b << 3) | tt;
            }
        }
        __syncthreads();
        if (tid == 0) wl[640] = cnt;
    }
}

// ---------------------------------------------------------------------------
// Kernel 1: main fused GEMM + epilogue.
// r13: A-DIRECT-FROM-L2. r11/r12 post-mortem: K-loop LDS demand (48 KB/blk/kt:
// 16 staged + 32 frag-read) exceeded MFMA demand (310cy), and pipes barely
// overlapped (time ~= serial sum of demands). Fix: Wg2 is pre-swizzled into
// per-lane fragment order, so A-frags come via coalesced global_load_dwordx4
// (volatile asm; issued at top of kt, waited with counted vmcnt post-ds_read
// ~250cy later => L2 latency covered). LDS carries only B: 8 KB stage + 16 KB
// read per blk/kt (~half of MFMA demand). 4-deep B buffer ring (32 KB, under
// the 33 KB epilogue Gs we already allocate) => SINGLE barrier per kt is
// WAR-safe: staging buf(kt+2) at iter kt only touches a buffer whose readers
// (iter kt-2) provably finished before barrier(kt-1) released. Counted vmcnt:
// pre-barrier vmcnt(8) (no-op steady; drains Bs0 at kt=0); post-ds_read
// vmcnt(2) leaves Bs(kt+2) in flight — never drain to 0 mid-loop.
// VGPR ~120 (64 acc + Af16 + Bf16 + addr) => 4 blocks/CU retained, LDS 33 KB.
// Grid stays (16,640) mt-fast: B-slab L2-shared by mt-siblings; Wg2 (2 MB)
// L2-resident by capacity on every XCD.
// ---------------------------------------------------------------------------
__global__ __launch_bounds__(256, 4)
void conv_gemm(const unsigned short* __restrict__ Wg, const unsigned short* __restrict__ Xg,
               const int* __restrict__ lengths, const int* __restrict__ wl,
               const float* __restrict__ cb1, const float* __restrict__ cb2,
               const float* __restrict__ cb3, const float* __restrict__ cb4,
               const float* __restrict__ cb5,
               float* __restrict__ pools) {
    __shared__ __align__(16) char smem[33024];               // max(4x8KB B-ring, Gs)
    unsigned short* ldsB = (unsigned short*)smem;            // 4 x 4096 ushorts
    float* Gs = (float*)smem;                                // 64*129 floats (epilogue)

    int cnt = wl[640];
    int wk = blockIdx.y;
    if (wk >= cnt) return;
    int item = wl[wk];
    int b = item >> 3, tt = item & 7;
    int mt = blockIdx.x;
    int n0 = tt * 124 - ((tt >> 2) * 112);   // {0,124,248,372,384}
    int L = lengths[b];
    int Leff = L > 5 ? L : 5;

    int tid = threadIdx.x;
    int wid = tid >> 6, lane = tid & 63;
    int wm = wid >> 1, wn = wid & 1;
    int llo = lane & 15, quad = lane >> 4;
    int psw = quad ^ ((llo >> 1) & 3);   // swizzled physical chunk for B frag reads

    int nb0 = b * 512 + n0;

    v4f acc[4][4];
    #pragma unroll
    for (int i = 0; i < 4; ++i)
        #pragma unroll
        for (int j = 0; j < 4; ++j) acc[i][j] = v4f{0.f, 0.f, 0.f, 0.f};

    // B staging: wave wid covers rows [wid*32, wid*32+32) in 2 insts of 16 rows
    int srow = lane >> 2;                           // 0..15
    int gchunk = (lane & 3) ^ ((lane >> 3) & 3);    // global chunk for physical slot lane&3
    const unsigned short* gB = Xg + (nb0 + wid * 32 + srow) * 512 + gchunk * 8;
    int sdst = (wid * 32) * 32;   // ushort offset of this wave's staging rows

    // A fragment stream: pre-swizzled Wg2, 16B/lane coalesced.
    // frag (kt,mi) for this wave: pA + kt*2048 + mi*512 (ushort units)
    const unsigned short* pA = Wg + (mt * 2 + wm) * 32768 + lane * 8;

    // prologue: stage B k-tiles 0,1 into ring bufs 0,1
    #pragma unroll
    for (int p = 0; p < 2; ++p) {
        #pragma unroll
        for (int q = 0; q < 2; ++q) {
            __builtin_amdgcn_global_load_lds(
                (const __attribute__((address_space(1))) unsigned int*)(gB + q * (16 * 512) + p * 32),
                (__attribute__((address_space(3))) unsigned int*)&ldsB[p * 4096 + sdst + q * 512],
                16, 0, 0);
        }
    }

    #pragma unroll 1
    for (int kt = 0; kt < 16; ++kt) {
        // A-frags for THIS kt: issue now, wait ~250cy later (post-ds_read vmcnt)
        v8s Af0, Af1, Af2, Af3;
        asm volatile("global_load_dwordx4 %0, %1, off"             : "=v"(Af0) : "v"(pA) : "memory");
        asm volatile("global_load_dwordx4 %0, %1, off offset:1024" : "=v"(Af1) : "v"(pA) : "memory");
        asm volatile("global_load_dwordx4 %0, %1, off offset:2048" : "=v"(Af2) : "v"(pA) : "memory");
        asm volatile("global_load_dwordx4 %0, %1, off offset:3072" : "=v"(Af3) : "v"(pA) : "memory");
        pA += 2048;

        // stage B(kt+2) into ring buf (kt+2)&3 (depth-2, stays in flight)
        if (kt < 14) {
            int bb = ((kt + 2) & 3) * 4096;
            #pragma unroll
            for (int q = 0; q < 2; ++q)
                __builtin_amdgcn_global_load_lds(
                    (const __attribute__((address_space(1))) unsigned int*)(gB + q * (16 * 512) + (kt + 2) * 32),
                    (__attribute__((address_space(3))) unsigned int*)&ldsB[bb + sdst + q * 512],
                    16, 0, 0);
        }

        // steady state: no-op (Bs(kt) drained at iter kt-1's vmcnt(2));
        // kt==0: drains Bs(0) issued in prologue.
        asm volatile("s_waitcnt vmcnt(8)" ::: "memory");
        __builtin_amdgcn_s_barrier();        // buf(kt&3) fully staged, all waves

        int boff = (kt & 3) * 4096;
        v8s Bf[4];
        #pragma unroll
        for (int ni = 0; ni < 4; ++ni)
            Bf[ni] = *(const v8s*)&ldsB[boff + (wn * 64 + ni * 16 + llo) * 32 + psw * 8];

        // wait A-frags (and Bs(kt+1), harmless — 1-iter old); keep Bs(kt+2) in flight
        if (kt < 14) asm volatile("s_waitcnt vmcnt(2)" ::: "memory");
        else         asm volatile("s_waitcnt vmcnt(0)" ::: "memory");
        __builtin_amdgcn_sched_barrier(0);   // rule #18: pin MFMA below the waits

        __builtin_amdgcn_s_setprio(1);
        #pragma unroll
        for (int ni = 0; ni < 4; ++ni) {
            acc[0][ni] = __builtin_amdgcn_mfma_f32_16x16x32_bf16(Af0, Bf[ni], acc[0][ni], 0, 0, 0);
            acc[1][ni] = __builtin_amdgcn_mfma_f32_16x16x32_bf16(Af1, Bf[ni], acc[1][ni], 0, 0, 0);
            acc[2][ni] = __builtin_amdgcn_mfma_f32_16x16x32_bf16(Af2, Bf[ni], acc[2][ni], 0, 0, 0);
            acc[3][ni] = __builtin_amdgcn_mfma_f32_16x16x32_bf16(Af3, Bf[ni], acc[3][ni], 0, 0, 0);
        }
        __builtin_amdgcn_s_setprio(0);
    }
    __syncthreads();   // all waves done with B-ring before Gs overwrites smem

    // ---- epilogue: 2 phases of 64 rows (4 filter groups each) ----
    const int basew[6] = {0, 0, 1, 3, 6, 10};

    #pragma unroll
    for (int phase = 0; phase < 2; ++phase) {
        if (wm == phase) {
            // C/D layout: col = lane&15, row = quad*4 + reg  [verified m89/m91]
            #pragma unroll
            for (int mi = 0; mi < 4; ++mi)
                #pragma unroll
                for (int ni = 0; ni < 4; ++ni)
                    #pragma unroll
                    for (int r = 0; r < 4; ++r)
                        Gs[(mi * 16 + quad * 4 + r) * 129 + wn * 64 + ni * 16 + llo] = acc[mi][ni][r];
        }
        __syncthreads();
        // pooling: wave wid handles filter group fl = wid of this phase
        {
            int fl = wid;
            int f = mt * 8 + phase * 4 + fl;
            #pragma unroll
            for (int w = 1; w <= 5; ++w) {
                float bias = (w == 1 ? cb1 : w == 2 ? cb2 : w == 3 ? cb3 : w == 4 ? cb4 : cb5)[f];
                int limv = Leff - w + 1 - n0;          // tile-local validity bound
                float vmax = -1.f;
                #pragma unroll
                for (int half = 0; half < 2; ++half) {
                    int t = half * 64 + lane;
                    if (t <= 128 - w && t < limv) {
                        float s = 0.f;
                        #pragma unroll
                        for (int j = 0; j < w; ++j)
                            s += Gs[(fl * 16 + basew[w] + j) * 129 + t + j];
                        s += bias;
                        s = fmaxf(s, 0.f);
                        vmax = fmaxf(vmax, s);
                    }
                }
                #pragma unroll
                for (int off = 32; off >= 1; off >>= 1)
                    vmax = fmaxf(vmax, __shfl_xor(vmax, off));
                if (lane == 0 && vmax >= 0.f)
                    atomicMax((int*)&pools[(b * 5 + (w - 1)) * NFC + f], __float_as_int(vmax));
            }
        }
        __syncthreads();
    }
}

// ---------------------------------------------------------------------------
// Kernel 2: per-batch dot(feat, v) + c -> sigmoid.  (unchanged)
// ---------------------------------------------------------------------------
__global__ void head(const float* __restrict__ pools, const float* __restrict__ v,
                     float* __restrict__ out) {
    int b = blockIdx.x;
    int tid = threadIdx.x;
    float s = 0.f;
    for (int k = tid; k < 640; k += 256) s += pools[b * 640 + k] * v[k];
    __shared__ float red[256];
    red[tid] = s;
    __syncthreads();
    for (int st = 128; st; st >>= 1) {
        if (tid < st) red[tid] += red[tid + st];
        __syncthreads();
    }
    if (tid == 0) out[b] = 1.f / (1.f + expf(-(red[0] + v[640])));
}

// ---------------------------------------------------------------------------
extern "C" void kernel_launch(void* const* d_in, const int* in_sizes, int n_in,
                              void* d_out, int out_size, void* d_ws, size_t ws_size,
                              hipStream_t stream) {
    const float* enc  = (const float*)d_in[0];
    const int* lens   = (const int*)d_in[1];
    const float* w1   = (const float*)d_in[2];
    const float* b1   = (const float*)d_in[3];
    const float* w2   = (const float*)d_in[4];
    const float* b2   = (const float*)d_in[5];
    const float* w3   = (const float*)d_in[6];
    const float* b3   = (const float*)d_in[7];
    const float* w4   = (const float*)d_in[8];
    const float* b4   = (const float*)d_in[9];
    const float* w5   = (const float*)d_in[10];
    const float* b5   = (const float*)d_in[11];
    const float* fc1w = (const float*)d_in[12];
    const float* fc1b = (const float*)d_in[13];
    const float* fc2w = (const float*)d_in[14];
    const float* fc2b = (const float*)d_in[15];
    float* out = (float*)d_out;

    // workspace layout
    unsigned short* Xg = (unsigned short*)d_ws;          // 33,554,432 ushorts (64 MB)
    unsigned short* Wg = Xg + 33554432;                  // 1,048,576 ushorts (2 MB, frag-order)
    float* pools  = (float*)(Wg + 1048576);              // 81,920 floats
    float* vbuf   = pools + 81920;                       // 641 floats
    int* wlist    = (int*)(vbuf + 641);                  // 641 ints

    prep_all<<<12610, 256, 0, stream>>>(enc, lens, Xg, w1, w2, w3, w4, w5, Wg, pools,
                                        fc1w, fc1b, fc2w, fc2b, vbuf, wlist);
    conv_gemm<<<dim3(16, 640), 256, 0, stream>>>(Wg, Xg, lens, wlist, b1, b2, b3, b4, b5, pools);
    head<<<128, 256, 0, stream>>>(pools, vbuf, out);
}

// Round 3
// 356.986 us; speedup vs baseline: 1.0685x; 1.0074x over previous
//
#include <hip/hip_runtime.h>
#include <hip/hip_bf16.h>

// Problem constants
#define TT 512   // T
#define BB 128   // B
#define HH 512   // H
#define NFC 128  // NF
// FS = 5

typedef short v8s __attribute__((ext_vector_type(8)));
typedef float v4f __attribute__((ext_vector_type(4)));

__device__ __forceinline__ unsigned short f2bf(float x) {
    unsigned u = __float_as_uint(x);
    unsigned r = (u + 0x7fffu + ((u >> 16) & 1u)) >> 16;
    return (unsigned short)r;
}

// ---------------------------------------------------------------------------
// Kernel 0: fused prep + gather.  (unchanged from r13)
// blocks [0,8192): gather X_all, [n][h] bf16, n=b*512+l; skip unread tiles.
// blocks [8192,12288): build Wg2: weight matrix PRE-SWIZZLED into per-lane
//   MFMA A-fragment order:  o = ((((mt*2+wm)*16 + kt)*4 + mi)*64 + lane)*8 + j
//   holds A[row = mt*128+wm*64+mi*16+(lane&15)][k = kt*32+(lane>>4)*8+j].
// blocks [12288,12608): zero pools.
// block 12608: collapse fc2∘fc1 into v[640] + c.
// block 12609: parallel worklist of active (b,tt) items (unordered).
// ---------------------------------------------------------------------------
__global__ void prep_all(const float* __restrict__ enc, const int* __restrict__ lengths,
                         unsigned short* __restrict__ Xg,
                         const float* __restrict__ w1, const float* __restrict__ w2,
                         const float* __restrict__ w3, const float* __restrict__ w4,
                         const float* __restrict__ w5, unsigned short* __restrict__ Wg,
                         float* __restrict__ pools,
                         const float* __restrict__ fc1w, const float* __restrict__ fc1b,
                         const float* __restrict__ fc2w, const float* __restrict__ fc2b,
                         float* __restrict__ v, int* __restrict__ wl) {
    int blk = blockIdx.x;
    int tid = threadIdx.x;
    if (blk < 8192) {
        __shared__ float tile[64 * 65];
        int b = blk >> 6;
        int lc = (blk >> 3) & 7;
        int hc = blk & 7;
        int L = lengths[b];
        int Leff = L > 5 ? L : 5;
        int l0 = lc * 64, h0 = hc * 64;
        if (l0 >= Leff + 127) return;     // never read by any active tile
        int lx = tid & 63;
        int hq = tid >> 6;                // 0..3
        #pragma unroll
        for (int r = 0; r < 16; ++r) {
            int hl = hq * 16 + r;         // local h
            int l = l0 + lx;
            float val = 0.f;
            if (l < L) {
                int i = (h0 + hl) * L + l;
                val = enc[(i >> 9) * (BB * HH) + b * HH + (i & 511)];
            }
            tile[hl * 65 + lx] = val;
        }
        __syncthreads();
        int hg = tid & 15;                // h quad within tile (4 bf16 = 8B)
        #pragma unroll
        for (int r = 0; r < 4; ++r) {
            int lloc = (tid >> 4) + r * 16;
            int n = b * 512 + l0 + lloc;
            ushort4 pk;
            pk.x = f2bf(tile[(hg * 4 + 0) * 65 + lloc]);
            pk.y = f2bf(tile[(hg * 4 + 1) * 65 + lloc]);
            pk.z = f2bf(tile[(hg * 4 + 2) * 65 + lloc]);
            pk.w = f2bf(tile[(hg * 4 + 3) * 65 + lloc]);
            *(ushort4*)&Xg[n * 512 + h0 + hg * 4] = pk;
        }
    } else if (blk < 12288) {
        int o = (blk - 8192) * 256 + tid;     // [0, 1,048,576)
        // fragment-order decomposition
        int j   = o & 7;
        int ln  = (o >> 3) & 63;
        int mi  = (o >> 9) & 3;
        int kt  = (o >> 11) & 15;
        int wmm = (o >> 15) & 1;
        int mtt = o >> 16;
        int row = mtt * 128 + wmm * 64 + mi * 16 + (ln & 15);   // 0..2047
        int k   = kt * 32 + (ln >> 4) * 8 + j;                  // 0..511
        int f = row >> 4, sl = row & 15;
        float val = 0.f;
        if (sl < 15) {
            int w, jj;
            if (sl < 1)       { w = 1; jj = sl; }
            else if (sl < 3)  { w = 2; jj = sl - 1; }
            else if (sl < 6)  { w = 3; jj = sl - 3; }
            else if (sl < 10) { w = 4; jj = sl - 6; }
            else              { w = 5; jj = sl - 10; }
            const float* wp = (w == 1) ? w1 : (w == 2) ? w2 : (w == 3) ? w3 : (w == 4) ? w4 : w5;
            val = wp[f * (HH * w) + k * w + jj];  // conv_w{w}[f,0,h=k,jj]
        }
        Wg[o] = f2bf(val);
    } else if (blk < 12608) {
        int i = (blk - 12288) * 256 + tid;
        if (i < BB * 5 * NFC) pools[i] = 0.f;
    } else if (blk == 12608) {
        for (int k = tid; k < 640; k += 256) {
            float s = 0.f;
            for (int o = 0; o < 100; ++o) s += fc2w[o] * fc1w[o * 640 + k];
            v[k] = s;
        }
        if (tid == 0) {
            float c = fc2b[0];
            for (int o = 0; o < 100; ++o) c += fc2w[o] * fc1b[o];
            v[640] = c;
        }
    } else {
        __shared__ int cnt;
        if (tid == 0) cnt = 0;
        __syncthreads();
        for (int it = tid; it < 640; it += 256) {
            int b = it / 5, tt = it % 5;
            int L = lengths[b];
            int Leff = L > 5 ? L : 5;
            int n0 = tt * 124 - ((tt >> 2) * 112);   // {0,124,248,372,384}
            if (n0 < Leff) {
                int pos = atomicAdd(&cnt, 1);
                wl[pos] = (b << 3) | tt;
            }
        }
        __syncthreads();
        if (tid == 0) wl[640] = cnt;
    }
}

// ---------------------------------------------------------------------------
// Kernel 1: main fused GEMM + epilogue.
// r14 changes on top of r13 (A-direct-from-L2, 125.5us, MfmaUtil 31%):
// (1) A-PREFETCH INTO MFMA PHASE: A(kt+1) frag-loads are issued inside the
//     MFMA cluster, each right after its old Af[mi] value's last consuming
//     MFMA (SSA WAR handled by compiler). The mid-kt vmcnt(2) now waits on
//     loads issued a FULL iteration ago (~800cy) instead of ~15 insts ago
//     (~200cy L2 latency exposed per kt in r13). vmcnt FIFO check (steady):
//     queue at mid-kt = [Bs(kt+1)2, A(kt)4, Bs(kt+2)2] -> vmcnt(2) drains
//     Bs(kt+1)+A(kt), keeps Bs(kt+2) in flight. Tail: vmcnt(0) at kt>=14.
//     Zero extra VGPR (loads reuse the Af registers).
// (2) EPILOGUE ds_read2: each lane owns the (t, t+64) half-pair, so the two
//     diagonal-sum reads per (w,j) share one base 64 dwords apart -> LLVM
//     merges to ds_read2_b32. 240 -> ~120 LDS read insts/block, pure C++.
// Everything else identical: 4-deep B-ring (32KB) + Gs overlay (33KB LDS),
// single barrier per kt (WAR-safe via ring depth), launch_bounds (256,4),
// grid (16,640) mt-fast.
// ---------------------------------------------------------------------------
__global__ __launch_bounds__(256, 4)
void conv_gemm(const unsigned short* __restrict__ Wg, const unsigned short* __restrict__ Xg,
               const int* __restrict__ lengths, const int* __restrict__ wl,
               const float* __restrict__ cb1, const float* __restrict__ cb2,
               const float* __restrict__ cb3, const float* __restrict__ cb4,
               const float* __restrict__ cb5,
               float* __restrict__ pools) {
    __shared__ __align__(16) char smem[33024];               // max(4x8KB B-ring, Gs)
    unsigned short* ldsB = (unsigned short*)smem;            // 4 x 4096 ushorts
    float* Gs = (float*)smem;                                // 64*129 floats (epilogue)

    int cnt = wl[640];
    int wk = blockIdx.y;
    if (wk >= cnt) return;
    int item = wl[wk];
    int b = item >> 3, tt = item & 7;
    int mt = blockIdx.x;
    int n0 = tt * 124 - ((tt >> 2) * 112);   // {0,124,248,372,384}
    int L = lengths[b];
    int Leff = L > 5 ? L : 5;

    int tid = threadIdx.x;
    int wid = tid >> 6, lane = tid & 63;
    int wm = wid >> 1, wn = wid & 1;
    int llo = lane & 15, quad = lane >> 4;
    int psw = quad ^ ((llo >> 1) & 3);   // swizzled physical chunk for B frag reads

    int nb0 = b * 512 + n0;

    v4f acc[4][4];
    #pragma unroll
    for (int i = 0; i < 4; ++i)
        #pragma unroll
        for (int j = 0; j < 4; ++j) acc[i][j] = v4f{0.f, 0.f, 0.f, 0.f};

    // B staging: wave wid covers rows [wid*32, wid*32+32) in 2 insts of 16 rows
    int srow = lane >> 2;                           // 0..15
    int gchunk = (lane & 3) ^ ((lane >> 3) & 3);    // global chunk for physical slot lane&3
    const unsigned short* gB = Xg + (nb0 + wid * 32 + srow) * 512 + gchunk * 8;
    int sdst = (wid * 32) * 32;   // ushort offset of this wave's staging rows

    // A fragment stream: pre-swizzled Wg2, 16B/lane coalesced from L2.
    // frag (kt,mi) for this wave: pA + kt*2048 + mi*512 (ushort units)
    const unsigned short* pA = Wg + (mt * 2 + wm) * 32768 + lane * 8;

    // prologue: stage B k-tiles 0,1 into ring bufs 0,1; then A(0) frags
    #pragma unroll
    for (int p = 0; p < 2; ++p) {
        #pragma unroll
        for (int q = 0; q < 2; ++q) {
            __builtin_amdgcn_global_load_lds(
                (const __attribute__((address_space(1))) unsigned int*)(gB + q * (16 * 512) + p * 32),
                (__attribute__((address_space(3))) unsigned int*)&ldsB[p * 4096 + sdst + q * 512],
                16, 0, 0);
        }
    }
    v8s Af0, Af1, Af2, Af3;
    asm volatile("global_load_dwordx4 %0, %1, off"             : "=v"(Af0) : "v"(pA) : "memory");
    asm volatile("global_load_dwordx4 %0, %1, off offset:1024" : "=v"(Af1) : "v"(pA) : "memory");
    asm volatile("global_load_dwordx4 %0, %1, off offset:2048" : "=v"(Af2) : "v"(pA) : "memory");
    asm volatile("global_load_dwordx4 %0, %1, off offset:3072" : "=v"(Af3) : "v"(pA) : "memory");

    #pragma unroll 1
    for (int kt = 0; kt < 16; ++kt) {
        // stage B(kt+2) into ring buf (kt+2)&3 (depth-2, stays in flight)
        if (kt < 14) {
            int bb = ((kt + 2) & 3) * 4096;
            #pragma unroll
            for (int q = 0; q < 2; ++q)
                __builtin_amdgcn_global_load_lds(
                    (const __attribute__((address_space(1))) unsigned int*)(gB + q * (16 * 512) + (kt + 2) * 32),
                    (__attribute__((address_space(3))) unsigned int*)&ldsB[bb + sdst + q * 512],
                    16, 0, 0);
        }

        // steady: no-op (Bs(kt) drained at kt-1 mid); kt==0: drains Bs(0).
        asm volatile("s_waitcnt vmcnt(8)" ::: "memory");
        __builtin_amdgcn_s_barrier();        // buf(kt&3) fully staged, all waves

        int boff = (kt & 3) * 4096;
        v8s Bf[4];
        #pragma unroll
        for (int ni = 0; ni < 4; ++ni)
            Bf[ni] = *(const v8s*)&ldsB[boff + (wn * 64 + ni * 16 + llo) * 32 + psw * 8];

        // wait A(kt) (issued a full iteration ago) + Bs(kt+1); keep Bs(kt+2)
        if (kt <= 13) asm volatile("s_waitcnt vmcnt(2)" ::: "memory");
        else          asm volatile("s_waitcnt vmcnt(0)" ::: "memory");
        __builtin_amdgcn_sched_barrier(0);   // rule #18: MFMA must not hoist above waits

        const unsigned short* pAn = pA + (kt + 1) * 2048;
        __builtin_amdgcn_s_setprio(1);
        // mi=0
        acc[0][0] = __builtin_amdgcn_mfma_f32_16x16x32_bf16(Af0, Bf[0], acc[0][0], 0, 0, 0);
        acc[0][1] = __builtin_amdgcn_mfma_f32_16x16x32_bf16(Af0, Bf[1], acc[0][1], 0, 0, 0);
        acc[0][2] = __builtin_amdgcn_mfma_f32_16x16x32_bf16(Af0, Bf[2], acc[0][2], 0, 0, 0);
        acc[0][3] = __builtin_amdgcn_mfma_f32_16x16x32_bf16(Af0, Bf[3], acc[0][3], 0, 0, 0);
        if (kt < 15)
            asm volatile("global_load_dwordx4 %0, %1, off"             : "=v"(Af0) : "v"(pAn) : "memory");
        // mi=1
        acc[1][0] = __builtin_amdgcn_mfma_f32_16x16x32_bf16(Af1, Bf[0], acc[1][0], 0, 0, 0);
        acc[1][1] = __builtin_amdgcn_mfma_f32_16x16x32_bf16(Af1, Bf[1], acc[1][1], 0, 0, 0);
        acc[1][2] = __builtin_amdgcn_mfma_f32_16x16x32_bf16(Af1, Bf[2], acc[1][2], 0, 0, 0);
        acc[1][3] = __builtin_amdgcn_mfma_f32_16x16x32_bf16(Af1, Bf[3], acc[1][3], 0, 0, 0);
        if (kt < 15)
            asm volatile("global_load_dwordx4 %0, %1, off offset:1024" : "=v"(Af1) : "v"(pAn) : "memory");
        // mi=2
        acc[2][0] = __builtin_amdgcn_mfma_f32_16x16x32_bf16(Af2, Bf[0], acc[2][0], 0, 0, 0);
        acc[2][1] = __builtin_amdgcn_mfma_f32_16x16x32_bf16(Af2, Bf[1], acc[2][1], 0, 0, 0);
        acc[2][2] = __builtin_amdgcn_mfma_f32_16x16x32_bf16(Af2, Bf[2], acc[2][2], 0, 0, 0);
        acc[2][3] = __builtin_amdgcn_mfma_f32_16x16x32_bf16(Af2, Bf[3], acc[2][3], 0, 0, 0);
        if (kt < 15)
            asm volatile("global_load_dwordx4 %0, %1, off offset:2048" : "=v"(Af2) : "v"(pAn) : "memory");
        // mi=3
        acc[3][0] = __builtin_amdgcn_mfma_f32_16x16x32_bf16(Af3, Bf[0], acc[3][0], 0, 0, 0);
        acc[3][1] = __builtin_amdgcn_mfma_f32_16x16x32_bf16(Af3, Bf[1], acc[3][1], 0, 0, 0);
        acc[3][2] = __builtin_amdgcn_mfma_f32_16x16x32_bf16(Af3, Bf[2], acc[3][2], 0, 0, 0);
        acc[3][3] = __builtin_amdgcn_mfma_f32_16x16x32_bf16(Af3, Bf[3], acc[3][3], 0, 0, 0);
        if (kt < 15)
            asm volatile("global_load_dwordx4 %0, %1, off offset:3072" : "=v"(Af3) : "v"(pAn) : "memory");
        __builtin_amdgcn_s_setprio(0);
    }
    __syncthreads();   // all waves done with B-ring before Gs overwrites smem

    // ---- epilogue: 2 phases of 64 rows (4 filter groups each) ----
    const int basew[6] = {0, 0, 1, 3, 6, 10};

    #pragma unroll
    for (int phase = 0; phase < 2; ++phase) {
        if (wm == phase) {
            // C/D layout: col = lane&15, row = quad*4 + reg  [verified m89/m91]
            #pragma unroll
            for (int mi = 0; mi < 4; ++mi)
                #pragma unroll
                for (int ni = 0; ni < 4; ++ni)
                    #pragma unroll
                    for (int r = 0; r < 4; ++r)
                        Gs[(mi * 16 + quad * 4 + r) * 129 + wn * 64 + ni * 16 + llo] = acc[mi][ni][r];
        }
        __syncthreads();
        // pooling: wave wid handles filter group fl = wid of this phase.
        // Each lane owns t = lane and t = lane+64; the two reads per (w,j)
        // share base + {130j, 130j+64} dwords -> ds_read2_b32 merge.
        {
            int fl = wid;
            int f = mt * 8 + phase * 4 + fl;
            #pragma unroll
            for (int w = 1; w <= 5; ++w) {
                float bias = (w == 1 ? cb1 : w == 2 ? cb2 : w == 3 ? cb3 : w == 4 ? cb4 : cb5)[f];
                int limv = Leff - w + 1 - n0;          // t < limv
                int lim = 128 - w; if (limv - 1 < lim) lim = limv - 1;   // t <= lim
                const float* gr = &Gs[(fl * 16 + basew[w]) * 129 + lane];
                float s0 = 0.f, s1 = 0.f;
                #pragma unroll
                for (int j = 0; j < w; ++j) {
                    s0 += gr[j * 130];        // G[row+j][lane+j]
                    s1 += gr[j * 130 + 64];   // G[row+j][lane+64+j]
                }
                float vmax = -1.f;
                if (lane <= lim)      vmax = fmaxf(vmax, fmaxf(s0 + bias, 0.f));
                if (lane + 64 <= lim) vmax = fmaxf(vmax, fmaxf(s1 + bias, 0.f));
                #pragma unroll
                for (int off = 32; off >= 1; off >>= 1)
                    vmax = fmaxf(vmax, __shfl_xor(vmax, off));
                if (lane == 0 && vmax >= 0.f)
                    atomicMax((int*)&pools[(b * 5 + (w - 1)) * NFC + f], __float_as_int(vmax));
            }
        }
        __syncthreads();
    }
}

// ---------------------------------------------------------------------------
// Kernel 2: per-batch dot(feat, v) + c -> sigmoid.  (unchanged)
// ---------------------------------------------------------------------------
__global__ void head(const float* __restrict__ pools, const float* __restrict__ v,
                     float* __restrict__ out) {
    int b = blockIdx.x;
    int tid = threadIdx.x;
    float s = 0.f;
    for (int k = tid; k < 640; k += 256) s += pools[b * 640 + k] * v[k];
    __shared__ float red[256];
    red[tid] = s;
    __syncthreads();
    for (int st = 128; st; st >>= 1) {
        if (tid < st) red[tid] += red[tid + st];
        __syncthreads();
    }
    if (tid == 0) out[b] = 1.f / (1.f + expf(-(red[0] + v[640])));
}

// ---------------------------------------------------------------------------
extern "C" void kernel_launch(void* const* d_in, const int* in_sizes, int n_in,
                              void* d_out, int out_size, void* d_ws, size_t ws_size,
                              hipStream_t stream) {
    const float* enc  = (const float*)d_in[0];
    const int* lens   = (const int*)d_in[1];
    const float* w1   = (const float*)d_in[2];
    const float* b1   = (const float*)d_in[3];
    const float* w2   = (const float*)d_in[4];
    const float* b2   = (const float*)d_in[5];
    const float* w3   = (const float*)d_in[6];
    const float* b3   = (const float*)d_in[7];
    const float* w4   = (const float*)d_in[8];
    const float* b4   = (const float*)d_in[9];
    const float* w5   = (const float*)d_in[10];
    const float* b5   = (const float*)d_in[11];
    const float* fc1w = (const float*)d_in[12];
    const float* fc1b = (const float*)d_in[13];
    const float* fc2w = (const float*)d_in[14];
    const float* fc2b = (const float*)d_in[15];
    float* out = (float*)d_out;

    // workspace layout
    unsigned short* Xg = (unsigned short*)d_ws;          // 33,554,432 ushorts (64 MB)
    unsigned short* Wg = Xg + 33554432;                  // 1,048,576 ushorts (2 MB, frag-order)
    float* pools  = (float*)(Wg + 1048576);              // 81,920 floats
    float* vbuf   = pools + 81920;                       // 641 floats
    int* wlist    = (int*)(vbuf + 641);                  // 641 ints

    prep_all<<<12610, 256, 0, stream>>>(enc, lens, Xg, w1, w2, w3, w4, w5, Wg, pools,
                                        fc1w, fc1b, fc2w, fc2b, vbuf, wlist);
    conv_gemm<<<dim3(16, 640), 256, 0, stream>>>(Wg, Xg, lens, wlist, b1, b2, b3, b4, b5, pools);
    head<<<128, 256, 0, stream>>>(pools, vbuf, out);
}

// Round 4
// 352.463 us; speedup vs baseline: 1.0822x; 1.0128x over previous
//
#include <hip/hip_runtime.h>
#include <hip/hip_bf16.h>

// Problem constants
#define TT 512   // T
#define BB 128   // B
#define HH 512   // H
#define NFC 128  // NF
// FS = 5

typedef short v8s __attribute__((ext_vector_type(8)));
typedef float v4f __attribute__((ext_vector_type(4)));

__device__ __forceinline__ unsigned short f2bf(float x) {
    unsigned u = __float_as_uint(x);
    unsigned r = (u + 0x7fffu + ((u >> 16) & 1u)) >> 16;
    return (unsigned short)r;
}

// ---------------------------------------------------------------------------
// Kernel 0: fused prep + gather.  (unchanged from r13)
// blocks [0,8192): gather X_all, [n][h] bf16, n=b*512+l; skip unread tiles.
// blocks [8192,12288): build Wg2: weight matrix PRE-SWIZZLED into per-lane
//   MFMA A-fragment order:  o = ((((mt*2+wm)*16 + kt)*4 + mi)*64 + lane)*8 + j
//   holds A[row = mt*128+wm*64+mi*16+(lane&15)][k = kt*32+(lane>>4)*8+j].
// blocks [12288,12608): zero pools.
// block 12608: collapse fc2∘fc1 into v[640] + c.
// block 12609: parallel worklist of active (b,tt) items (unordered).
// ---------------------------------------------------------------------------
__global__ void prep_all(const float* __restrict__ enc, const int* __restrict__ lengths,
                         unsigned short* __restrict__ Xg,
                         const float* __restrict__ w1, const float* __restrict__ w2,
                         const float* __restrict__ w3, const float* __restrict__ w4,
                         const float* __restrict__ w5, unsigned short* __restrict__ Wg,
                         float* __restrict__ pools,
                         const float* __restrict__ fc1w, const float* __restrict__ fc1b,
                         const float* __restrict__ fc2w, const float* __restrict__ fc2b,
                         float* __restrict__ v, int* __restrict__ wl) {
    int blk = blockIdx.x;
    int tid = threadIdx.x;
    if (blk < 8192) {
        __shared__ float tile[64 * 65];
        int b = blk >> 6;
        int lc = (blk >> 3) & 7;
        int hc = blk & 7;
        int L = lengths[b];
        int Leff = L > 5 ? L : 5;
        int l0 = lc * 64, h0 = hc * 64;
        if (l0 >= Leff + 127) return;     // never read by any active tile
        int lx = tid & 63;
        int hq = tid >> 6;                // 0..3
        #pragma unroll
        for (int r = 0; r < 16; ++r) {
            int hl = hq * 16 + r;         // local h
            int l = l0 + lx;
            float val = 0.f;
            if (l < L) {
                int i = (h0 + hl) * L + l;
                val = enc[(i >> 9) * (BB * HH) + b * HH + (i & 511)];
            }
            tile[hl * 65 + lx] = val;
        }
        __syncthreads();
        int hg = tid & 15;                // h quad within tile (4 bf16 = 8B)
        #pragma unroll
        for (int r = 0; r < 4; ++r) {
            int lloc = (tid >> 4) + r * 16;
            int n = b * 512 + l0 + lloc;
            ushort4 pk;
            pk.x = f2bf(tile[(hg * 4 + 0) * 65 + lloc]);
            pk.y = f2bf(tile[(hg * 4 + 1) * 65 + lloc]);
            pk.z = f2bf(tile[(hg * 4 + 2) * 65 + lloc]);
            pk.w = f2bf(tile[(hg * 4 + 3) * 65 + lloc]);
            *(ushort4*)&Xg[n * 512 + h0 + hg * 4] = pk;
        }
    } else if (blk < 12288) {
        int o = (blk - 8192) * 256 + tid;     // [0, 1,048,576)
        // fragment-order decomposition
        int j   = o & 7;
        int ln  = (o >> 3) & 63;
        int mi  = (o >> 9) & 3;
        int kt  = (o >> 11) & 15;
        int wmm = (o >> 15) & 1;
        int mtt = o >> 16;
        int row = mtt * 128 + wmm * 64 + mi * 16 + (ln & 15);   // 0..2047
        int k   = kt * 32 + (ln >> 4) * 8 + j;                  // 0..511
        int f = row >> 4, sl = row & 15;
        float val = 0.f;
        if (sl < 15) {
            int w, jj;
            if (sl < 1)       { w = 1; jj = sl; }
            else if (sl < 3)  { w = 2; jj = sl - 1; }
            else if (sl < 6)  { w = 3; jj = sl - 3; }
            else if (sl < 10) { w = 4; jj = sl - 6; }
            else              { w = 5; jj = sl - 10; }
            const float* wp = (w == 1) ? w1 : (w == 2) ? w2 : (w == 3) ? w3 : (w == 4) ? w4 : w5;
            val = wp[f * (HH * w) + k * w + jj];  // conv_w{w}[f,0,h=k,jj]
        }
        Wg[o] = f2bf(val);
    } else if (blk < 12608) {
        int i = (blk - 12288) * 256 + tid;
        if (i < BB * 5 * NFC) pools[i] = 0.f;
    } else if (blk == 12608) {
        for (int k = tid; k < 640; k += 256) {
            float s = 0.f;
            for (int o = 0; o < 100; ++o) s += fc2w[o] * fc1w[o * 640 + k];
            v[k] = s;
        }
        if (tid == 0) {
            float c = fc2b[0];
            for (int o = 0; o < 100; ++o) c += fc2w[o] * fc1b[o];
            v[640] = c;
        }
    } else {
        __shared__ int cnt;
        if (tid == 0) cnt = 0;
        __syncthreads();
        for (int it = tid; it < 640; it += 256) {
            int b = it / 5, tt = it % 5;
            int L = lengths[b];
            int Leff = L > 5 ? L : 5;
            int n0 = tt * 124 - ((tt >> 2) * 112);   // {0,124,248,372,384}
            if (n0 < Leff) {
                int pos = atomicAdd(&cnt, 1);
                wl[pos] = (b << 3) | tt;
            }
        }
        __syncthreads();
        if (tid == 0) wl[640] = cnt;
    }
}

// ---------------------------------------------------------------------------
// Kernel 1: main fused GEMM + epilogue.
// r15 change on top of r14: XCD-ALIGNED FLAT GRID. r11-r14 all show FETCH
// 162 MB vs ~48 MB compulsory (3.4x) with HBM at 1.4 TB/s and NOTHING
// saturated (Mfma 32 / VALU 27 / L2-path ~50%): B-stage loads keep missing
// L2 and the K-loop waits (1-kt tolerance) expose HBM latency every kt.
// Root cause: grid (16,640) x-fast => item wk's 16 mt-siblings have linear
// ids 16*wk+x => round-robin XCD (id%8) scatters them over ALL 8 XCDs, and
// each XCD's resident set spans ~64 DIFFERENT items (~8 MB >> 4 MB L2).
// Fix: 1-D grid, g = ((wk>>3)*16 + mt)*8 + (wk&7): all 16 siblings of a
// wl-position sit in ONE mod-8 class, consecutive within it => same XCD,
// co-resident => slab fetched ~once, working set ~8 items x 128KB + Wg 2MB
// = 3 MB <= 4 MB L2. 640 = 80*8 exactly; balance preserved.
// K-loop/epilogue identical to r14 (A-direct-from-L2 + A-prefetch-in-MFMA,
// 4-deep B-ring, counted vmcnt, single barrier per kt, (256,4), LDS 33KB).
// ---------------------------------------------------------------------------
__global__ __launch_bounds__(256, 4)
void conv_gemm(const unsigned short* __restrict__ Wg, const unsigned short* __restrict__ Xg,
               const int* __restrict__ lengths, const int* __restrict__ wl,
               const float* __restrict__ cb1, const float* __restrict__ cb2,
               const float* __restrict__ cb3, const float* __restrict__ cb4,
               const float* __restrict__ cb5,
               float* __restrict__ pools) {
    __shared__ __align__(16) char smem[33024];               // max(4x8KB B-ring, Gs)
    unsigned short* ldsB = (unsigned short*)smem;            // 4 x 4096 ushorts
    float* Gs = (float*)smem;                                // 64*129 floats (epilogue)

    int cnt = wl[640];
    // XCD-aligned decode: siblings of one wl-position share g&7 (same XCD
    // under round-robin) and are consecutive within the class.
    int g = blockIdx.x;
    int xcd = g & 7;
    int q = g >> 3;
    int mt = q & 15;
    int wk = (q >> 4) * 8 + xcd;
    if (wk >= cnt) return;
    int item = wl[wk];
    int b = item >> 3, tt = item & 7;
    int n0 = tt * 124 - ((tt >> 2) * 112);   // {0,124,248,372,384}
    int L = lengths[b];
    int Leff = L > 5 ? L : 5;

    int tid = threadIdx.x;
    int wid = tid >> 6, lane = tid & 63;
    int wm = wid >> 1, wn = wid & 1;
    int llo = lane & 15, quad = lane >> 4;
    int psw = quad ^ ((llo >> 1) & 3);   // swizzled physical chunk for B frag reads

    int nb0 = b * 512 + n0;

    v4f acc[4][4];
    #pragma unroll
    for (int i = 0; i < 4; ++i)
        #pragma unroll
        for (int j = 0; j < 4; ++j) acc[i][j] = v4f{0.f, 0.f, 0.f, 0.f};

    // B staging: wave wid covers rows [wid*32, wid*32+32) in 2 insts of 16 rows
    int srow = lane >> 2;                           // 0..15
    int gchunk = (lane & 3) ^ ((lane >> 3) & 3);    // global chunk for physical slot lane&3
    const unsigned short* gB = Xg + (nb0 + wid * 32 + srow) * 512 + gchunk * 8;
    int sdst = (wid * 32) * 32;   // ushort offset of this wave's staging rows

    // A fragment stream: pre-swizzled Wg2, 16B/lane coalesced from L2.
    // frag (kt,mi) for this wave: pA + kt*2048 + mi*512 (ushort units)
    const unsigned short* pA = Wg + (mt * 2 + wm) * 32768 + lane * 8;

    // prologue: stage B k-tiles 0,1 into ring bufs 0,1; then A(0) frags
    #pragma unroll
    for (int p = 0; p < 2; ++p) {
        #pragma unroll
        for (int q2 = 0; q2 < 2; ++q2) {
            __builtin_amdgcn_global_load_lds(
                (const __attribute__((address_space(1))) unsigned int*)(gB + q2 * (16 * 512) + p * 32),
                (__attribute__((address_space(3))) unsigned int*)&ldsB[p * 4096 + sdst + q2 * 512],
                16, 0, 0);
        }
    }
    v8s Af0, Af1, Af2, Af3;
    asm volatile("global_load_dwordx4 %0, %1, off"             : "=v"(Af0) : "v"(pA) : "memory");
    asm volatile("global_load_dwordx4 %0, %1, off offset:1024" : "=v"(Af1) : "v"(pA) : "memory");
    asm volatile("global_load_dwordx4 %0, %1, off offset:2048" : "=v"(Af2) : "v"(pA) : "memory");
    asm volatile("global_load_dwordx4 %0, %1, off offset:3072" : "=v"(Af3) : "v"(pA) : "memory");

    #pragma unroll 1
    for (int kt = 0; kt < 16; ++kt) {
        // stage B(kt+2) into ring buf (kt+2)&3 (depth-2, stays in flight)
        if (kt < 14) {
            int bb = ((kt + 2) & 3) * 4096;
            #pragma unroll
            for (int q2 = 0; q2 < 2; ++q2)
                __builtin_amdgcn_global_load_lds(
                    (const __attribute__((address_space(1))) unsigned int*)(gB + q2 * (16 * 512) + (kt + 2) * 32),
                    (__attribute__((address_space(3))) unsigned int*)&ldsB[bb + sdst + q2 * 512],
                    16, 0, 0);
        }

        // steady: no-op (Bs(kt) drained at kt-1 mid); kt==0: drains Bs(0).
        asm volatile("s_waitcnt vmcnt(8)" ::: "memory");
        __builtin_amdgcn_s_barrier();        // buf(kt&3) fully staged, all waves

        int boff = (kt & 3) * 4096;
        v8s Bf[4];
        #pragma unroll
        for (int ni = 0; ni < 4; ++ni)
            Bf[ni] = *(const v8s*)&ldsB[boff + (wn * 64 + ni * 16 + llo) * 32 + psw * 8];

        // wait A(kt) (issued a full iteration ago) + Bs(kt+1); keep Bs(kt+2)
        if (kt <= 13) asm volatile("s_waitcnt vmcnt(2)" ::: "memory");
        else          asm volatile("s_waitcnt vmcnt(0)" ::: "memory");
        __builtin_amdgcn_sched_barrier(0);   // rule #18: MFMA must not hoist above waits

        const unsigned short* pAn = pA + (kt + 1) * 2048;
        __builtin_amdgcn_s_setprio(1);
        // mi=0
        acc[0][0] = __builtin_amdgcn_mfma_f32_16x16x32_bf16(Af0, Bf[0], acc[0][0], 0, 0, 0);
        acc[0][1] = __builtin_amdgcn_mfma_f32_16x16x32_bf16(Af0, Bf[1], acc[0][1], 0, 0, 0);
        acc[0][2] = __builtin_amdgcn_mfma_f32_16x16x32_bf16(Af0, Bf[2], acc[0][2], 0, 0, 0);
        acc[0][3] = __builtin_amdgcn_mfma_f32_16x16x32_bf16(Af0, Bf[3], acc[0][3], 0, 0, 0);
        if (kt < 15)
            asm volatile("global_load_dwordx4 %0, %1, off"             : "=v"(Af0) : "v"(pAn) : "memory");
        // mi=1
        acc[1][0] = __builtin_amdgcn_mfma_f32_16x16x32_bf16(Af1, Bf[0], acc[1][0], 0, 0, 0);
        acc[1][1] = __builtin_amdgcn_mfma_f32_16x16x32_bf16(Af1, Bf[1], acc[1][1], 0, 0, 0);
        acc[1][2] = __builtin_amdgcn_mfma_f32_16x16x32_bf16(Af1, Bf[2], acc[1][2], 0, 0, 0);
        acc[1][3] = __builtin_amdgcn_mfma_f32_16x16x32_bf16(Af1, Bf[3], acc[1][3], 0, 0, 0);
        if (kt < 15)
            asm volatile("global_load_dwordx4 %0, %1, off offset:1024" : "=v"(Af1) : "v"(pAn) : "memory");
        // mi=2
        acc[2][0] = __builtin_amdgcn_mfma_f32_16x16x32_bf16(Af2, Bf[0], acc[2][0], 0, 0, 0);
        acc[2][1] = __builtin_amdgcn_mfma_f32_16x16x32_bf16(Af2, Bf[1], acc[2][1], 0, 0, 0);
        acc[2][2] = __builtin_amdgcn_mfma_f32_16x16x32_bf16(Af2, Bf[2], acc[2][2], 0, 0, 0);
        acc[2][3] = __builtin_amdgcn_mfma_f32_16x16x32_bf16(Af2, Bf[3], acc[2][3], 0, 0, 0);
        if (kt < 15)
            asm volatile("global_load_dwordx4 %0, %1, off offset:2048" : "=v"(Af2) : "v"(pAn) : "memory");
        // mi=3
        acc[3][0] = __builtin_amdgcn_mfma_f32_16x16x32_bf16(Af3, Bf[0], acc[3][0], 0, 0, 0);
        acc[3][1] = __builtin_amdgcn_mfma_f32_16x16x32_bf16(Af3, Bf[1], acc[3][1], 0, 0, 0);
        acc[3][2] = __builtin_amdgcn_mfma_f32_16x16x32_bf16(Af3, Bf[2], acc[3][2], 0, 0, 0);
        acc[3][3] = __builtin_amdgcn_mfma_f32_16x16x32_bf16(Af3, Bf[3], acc[3][3], 0, 0, 0);
        if (kt < 15)
            asm volatile("global_load_dwordx4 %0, %1, off offset:3072" : "=v"(Af3) : "v"(pAn) : "memory");
        __builtin_amdgcn_s_setprio(0);
    }
    __syncthreads();   // all waves done with B-ring before Gs overwrites smem

    // ---- epilogue: 2 phases of 64 rows (4 filter groups each) ----
    const int basew[6] = {0, 0, 1, 3, 6, 10};

    #pragma unroll
    for (int phase = 0; phase < 2; ++phase) {
        if (wm == phase) {
            // C/D layout: col = lane&15, row = quad*4 + reg  [verified m89/m91]
            #pragma unroll
            for (int mi = 0; mi < 4; ++mi)
                #pragma unroll
                for (int ni = 0; ni < 4; ++ni)
                    #pragma unroll
                    for (int r = 0; r < 4; ++r)
                        Gs[(mi * 16 + quad * 4 + r) * 129 + wn * 64 + ni * 16 + llo] = acc[mi][ni][r];
        }
        __syncthreads();
        // pooling: wave wid handles filter group fl = wid of this phase.
        // Each lane owns t = lane and t = lane+64; the two reads per (w,j)
        // share base + {130j, 130j+64} dwords -> ds_read2_b32 merge.
        {
            int fl = wid;
            int f = mt * 8 + phase * 4 + fl;
            #pragma unroll
            for (int w = 1; w <= 5; ++w) {
                float bias = (w == 1 ? cb1 : w == 2 ? cb2 : w == 3 ? cb3 : w == 4 ? cb4 : cb5)[f];
                int limv = Leff - w + 1 - n0;          // t < limv
                int lim = 128 - w; if (limv - 1 < lim) lim = limv - 1;   // t <= lim
                const float* gr = &Gs[(fl * 16 + basew[w]) * 129 + lane];
                float s0 = 0.f, s1 = 0.f;
                #pragma unroll
                for (int j = 0; j < w; ++j) {
                    s0 += gr[j * 130];        // G[row+j][lane+j]
                    s1 += gr[j * 130 + 64];   // G[row+j][lane+64+j]
                }
                float vmax = -1.f;
                if (lane <= lim)      vmax = fmaxf(vmax, fmaxf(s0 + bias, 0.f));
                if (lane + 64 <= lim) vmax = fmaxf(vmax, fmaxf(s1 + bias, 0.f));
                #pragma unroll
                for (int off = 32; off >= 1; off >>= 1)
                    vmax = fmaxf(vmax, __shfl_xor(vmax, off));
                if (lane == 0 && vmax >= 0.f)
                    atomicMax((int*)&pools[(b * 5 + (w - 1)) * NFC + f], __float_as_int(vmax));
            }
        }
        __syncthreads();
    }
}

// ---------------------------------------------------------------------------
// Kernel 2: per-batch dot(feat, v) + c -> sigmoid.  (unchanged)
// ---------------------------------------------------------------------------
__global__ void head(const float* __restrict__ pools, const float* __restrict__ v,
                     float* __restrict__ out) {
    int b = blockIdx.x;
    int tid = threadIdx.x;
    float s = 0.f;
    for (int k = tid; k < 640; k += 256) s += pools[b * 640 + k] * v[k];
    __shared__ float red[256];
    red[tid] = s;
    __syncthreads();
    for (int st = 128; st; st >>= 1) {
        if (tid < st) red[tid] += red[tid + st];
        __syncthreads();
    }
    if (tid == 0) out[b] = 1.f / (1.f + expf(-(red[0] + v[640])));
}

// ---------------------------------------------------------------------------
extern "C" void kernel_launch(void* const* d_in, const int* in_sizes, int n_in,
                              void* d_out, int out_size, void* d_ws, size_t ws_size,
                              hipStream_t stream) {
    const float* enc  = (const float*)d_in[0];
    const int* lens   = (const int*)d_in[1];
    const float* w1   = (const float*)d_in[2];
    const float* b1   = (const float*)d_in[3];
    const float* w2   = (const float*)d_in[4];
    const float* b2   = (const float*)d_in[5];
    const float* w3   = (const float*)d_in[6];
    const float* b3   = (const float*)d_in[7];
    const float* w4   = (const float*)d_in[8];
    const float* b4   = (const float*)d_in[9];
    const float* w5   = (const float*)d_in[10];
    const float* b5   = (const float*)d_in[11];
    const float* fc1w = (const float*)d_in[12];
    const float* fc1b = (const float*)d_in[13];
    const float* fc2w = (const float*)d_in[14];
    const float* fc2b = (const float*)d_in[15];
    float* out = (float*)d_out;

    // workspace layout
    unsigned short* Xg = (unsigned short*)d_ws;          // 33,554,432 ushorts (64 MB)
    unsigned short* Wg = Xg + 33554432;                  // 1,048,576 ushorts (2 MB, frag-order)
    float* pools  = (float*)(Wg + 1048576);              // 81,920 floats
    float* vbuf   = pools + 81920;                       // 641 floats
    int* wlist    = (int*)(vbuf + 641);                  // 641 ints

    prep_all<<<12610, 256, 0, stream>>>(enc, lens, Xg, w1, w2, w3, w4, w5, Wg, pools,
                                        fc1w, fc1b, fc2w, fc2b, vbuf, wlist);
    conv_gemm<<<10240, 256, 0, stream>>>(Wg, Xg, lens, wlist, b1, b2, b3, b4, b5, pools);
    head<<<128, 256, 0, stream>>>(pools, vbuf, out);
}

// Round 5
// 343.179 us; speedup vs baseline: 1.1115x; 1.0271x over previous
//
#include <hip/hip_runtime.h>
#include <hip/hip_bf16.h>

// Problem constants
#define TT 512   // T
#define BB 128   // B
#define HH 512   // H
#define NFC 128  // NF
// FS = 5

typedef short v8s __attribute__((ext_vector_type(8)));
typedef float v4f __attribute__((ext_vector_type(4)));

__device__ __forceinline__ unsigned short f2bf(float x) {
    unsigned u = __float_as_uint(x);
    unsigned r = (u + 0x7fffu + ((u >> 16) & 1u)) >> 16;
    return (unsigned short)r;
}

// ---------------------------------------------------------------------------
// Kernel 0: fused prep + gather.  (unchanged from r13)
// ---------------------------------------------------------------------------
__global__ void prep_all(const float* __restrict__ enc, const int* __restrict__ lengths,
                         unsigned short* __restrict__ Xg,
                         const float* __restrict__ w1, const float* __restrict__ w2,
                         const float* __restrict__ w3, const float* __restrict__ w4,
                         const float* __restrict__ w5, unsigned short* __restrict__ Wg,
                         float* __restrict__ pools,
                         const float* __restrict__ fc1w, const float* __restrict__ fc1b,
                         const float* __restrict__ fc2w, const float* __restrict__ fc2b,
                         float* __restrict__ v, int* __restrict__ wl) {
    int blk = blockIdx.x;
    int tid = threadIdx.x;
    if (blk < 8192) {
        __shared__ float tile[64 * 65];
        int b = blk >> 6;
        int lc = (blk >> 3) & 7;
        int hc = blk & 7;
        int L = lengths[b];
        int Leff = L > 5 ? L : 5;
        int l0 = lc * 64, h0 = hc * 64;
        if (l0 >= Leff + 127) return;     // never read by any active tile
        int lx = tid & 63;
        int hq = tid >> 6;                // 0..3
        #pragma unroll
        for (int r = 0; r < 16; ++r) {
            int hl = hq * 16 + r;         // local h
            int l = l0 + lx;
            float val = 0.f;
            if (l < L) {
                int i = (h0 + hl) * L + l;
                val = enc[(i >> 9) * (BB * HH) + b * HH + (i & 511)];
            }
            tile[hl * 65 + lx] = val;
        }
        __syncthreads();
        int hg = tid & 15;                // h quad within tile (4 bf16 = 8B)
        #pragma unroll
        for (int r = 0; r < 4; ++r) {
            int lloc = (tid >> 4) + r * 16;
            int n = b * 512 + l0 + lloc;
            ushort4 pk;
            pk.x = f2bf(tile[(hg * 4 + 0) * 65 + lloc]);
            pk.y = f2bf(tile[(hg * 4 + 1) * 65 + lloc]);
            pk.z = f2bf(tile[(hg * 4 + 2) * 65 + lloc]);
            pk.w = f2bf(tile[(hg * 4 + 3) * 65 + lloc]);
            *(ushort4*)&Xg[n * 512 + h0 + hg * 4] = pk;
        }
    } else if (blk < 12288) {
        int o = (blk - 8192) * 256 + tid;     // [0, 1,048,576)
        // fragment-order decomposition
        int j   = o & 7;
        int ln  = (o >> 3) & 63;
        int mi  = (o >> 9) & 3;
        int kt  = (o >> 11) & 15;
        int wmm = (o >> 15) & 1;
        int mtt = o >> 16;
        int row = mtt * 128 + wmm * 64 + mi * 16 + (ln & 15);   // 0..2047
        int k   = kt * 32 + (ln >> 4) * 8 + j;                  // 0..511
        int f = row >> 4, sl = row & 15;
        float val = 0.f;
        if (sl < 15) {
            int w, jj;
            if (sl < 1)       { w = 1; jj = sl; }
            else if (sl < 3)  { w = 2; jj = sl - 1; }
            else if (sl < 6)  { w = 3; jj = sl - 3; }
            else if (sl < 10) { w = 4; jj = sl - 6; }
            else              { w = 5; jj = sl - 10; }
            const float* wp = (w == 1) ? w1 : (w == 2) ? w2 : (w == 3) ? w3 : (w == 4) ? w4 : w5;
            val = wp[f * (HH * w) + k * w + jj];  // conv_w{w}[f,0,h=k,jj]
        }
        Wg[o] = f2bf(val);
    } else if (blk < 12608) {
        int i = (blk - 12288) * 256 + tid;
        if (i < BB * 5 * NFC) pools[i] = 0.f;
    } else if (blk == 12608) {
        for (int k = tid; k < 640; k += 256) {
            float s = 0.f;
            for (int o = 0; o < 100; ++o) s += fc2w[o] * fc1w[o * 640 + k];
            v[k] = s;
        }
        if (tid == 0) {
            float c = fc2b[0];
            for (int o = 0; o < 100; ++o) c += fc2w[o] * fc1b[o];
            v[640] = c;
        }
    } else {
        __shared__ int cnt;
        if (tid == 0) cnt = 0;
        __syncthreads();
        for (int it = tid; it < 640; it += 256) {
            int b = it / 5, tt = it % 5;
            int L = lengths[b];
            int Leff = L > 5 ? L : 5;
            int n0 = tt * 124 - ((tt >> 2) * 112);   // {0,124,248,372,384}
            if (n0 < Leff) {
                int pos = atomicAdd(&cnt, 1);
                wl[pos] = (b << 3) | tt;
            }
        }
        __syncthreads();
        if (tid == 0) wl[640] = cnt;
    }
}

// ---------------------------------------------------------------------------
// Kernel 1: main fused GEMM + epilogue.
// r16 changes on top of r15 (XCD-aligned grid, 118us, MfmaUtil 34%):
// (1) EARLY A-ISSUE + DOUBLE-BANKED Af REGS. r14's "prefetch" still issued
//     the LAST A-frag at the END of the MFMA cluster, ~180cy before the next
//     iteration's vmcnt(2) -> exposed L2 latency every kt (the invariant
//     T~900cy across r11-r15). Now all 4 A(kt+1) loads issue together right
//     after the mid-kt vmcnt, into the ALTERNATE Af bank (AfA/AfB, +16 VGPR)
//     -> issue-to-wait gap ~400-450cy. vmcnt ladder UNCHANGED (steady queue
//     at mid-kt = [Bs(kt+1):2, A(kt):4, Bs(kt+2):2] -> vmcnt(2); kt>=14 ->
//     vmcnt(0)). Loop hand-unrolled x2 for compile-time bank roles.
// (2) EPILOGUE PARALLEL BUTTERFLIES: the 5 per-w shuffle reductions were
//     serial 6-deep cross-lane chains (~2-4K cy/block). Now 5 independent
//     chains interleaved per step; atomics spread over lanes 0..4.
// Everything else identical: A-direct-from-L2 (frag-order Wg2), 4-deep
// B-ring + Gs overlay (33KB LDS), single barrier per kt, (256,4), 1-D
// XCD-aligned grid.
// ---------------------------------------------------------------------------
#define STAGE_B(KT) do {                                                          \
    int bb_ = (((KT) + 2) & 3) * 4096;                                            \
    __builtin_amdgcn_global_load_lds(                                             \
        (const __attribute__((address_space(1))) unsigned int*)(gB + ((KT) + 2) * 32),            \
        (__attribute__((address_space(3))) unsigned int*)&ldsB[bb_ + sdst],       \
        16, 0, 0);                                                                \
    __builtin_amdgcn_global_load_lds(                                             \
        (const __attribute__((address_space(1))) unsigned int*)(gB + 16 * 512 + ((KT) + 2) * 32), \
        (__attribute__((address_space(3))) unsigned int*)&ldsB[bb_ + sdst + 512], \
        16, 0, 0);                                                                \
} while (0)

#define KT_BODY(KT, AC0, AC1, AC2, AC3, AL0, AL1, AL2, AL3, STAGE, LOADA, VMSTR) do { \
    if (STAGE) STAGE_B(KT);                                                       \
    asm volatile("s_waitcnt vmcnt(8)" ::: "memory");                              \
    __builtin_amdgcn_s_barrier();                                                 \
    int boff_ = ((KT) & 3) * 4096;                                                \
    v8s Bf0 = *(const v8s*)&ldsB[boff_ + (wn * 64 +  0 + llo) * 32 + psw * 8];    \
    v8s Bf1 = *(const v8s*)&ldsB[boff_ + (wn * 64 + 16 + llo) * 32 + psw * 8];    \
    v8s Bf2 = *(const v8s*)&ldsB[boff_ + (wn * 64 + 32 + llo) * 32 + psw * 8];    \
    v8s Bf3 = *(const v8s*)&ldsB[boff_ + (wn * 64 + 48 + llo) * 32 + psw * 8];    \
    asm volatile("s_waitcnt " VMSTR ::: "memory");                                \
    __builtin_amdgcn_sched_barrier(0);                                            \
    if (LOADA) {                                                                  \
        asm volatile("global_load_dwordx4 %0, %1, off"             : "=v"(AL0) : "v"(pAc) : "memory"); \
        asm volatile("global_load_dwordx4 %0, %1, off offset:1024" : "=v"(AL1) : "v"(pAc) : "memory"); \
        asm volatile("global_load_dwordx4 %0, %1, off offset:2048" : "=v"(AL2) : "v"(pAc) : "memory"); \
        asm volatile("global_load_dwordx4 %0, %1, off offset:3072" : "=v"(AL3) : "v"(pAc) : "memory"); \
        pAc += 2048;                                                              \
    }                                                                             \
    __builtin_amdgcn_s_setprio(1);                                                \
    acc[0][0] = __builtin_amdgcn_mfma_f32_16x16x32_bf16(AC0, Bf0, acc[0][0], 0, 0, 0); \
    acc[0][1] = __builtin_amdgcn_mfma_f32_16x16x32_bf16(AC0, Bf1, acc[0][1], 0, 0, 0); \
    acc[0][2] = __builtin_amdgcn_mfma_f32_16x16x32_bf16(AC0, Bf2, acc[0][2], 0, 0, 0); \
    acc[0][3] = __builtin_amdgcn_mfma_f32_16x16x32_bf16(AC0, Bf3, acc[0][3], 0, 0, 0); \
    acc[1][0] = __builtin_amdgcn_mfma_f32_16x16x32_bf16(AC1, Bf0, acc[1][0], 0, 0, 0); \
    acc[1][1] = __builtin_amdgcn_mfma_f32_16x16x32_bf16(AC1, Bf1, acc[1][1], 0, 0, 0); \
    acc[1][2] = __builtin_amdgcn_mfma_f32_16x16x32_bf16(AC1, Bf2, acc[1][2], 0, 0, 0); \
    acc[1][3] = __builtin_amdgcn_mfma_f32_16x16x32_bf16(AC1, Bf3, acc[1][3], 0, 0, 0); \
    acc[2][0] = __builtin_amdgcn_mfma_f32_16x16x32_bf16(AC2, Bf0, acc[2][0], 0, 0, 0); \
    acc[2][1] = __builtin_amdgcn_mfma_f32_16x16x32_bf16(AC2, Bf1, acc[2][1], 0, 0, 0); \
    acc[2][2] = __builtin_amdgcn_mfma_f32_16x16x32_bf16(AC2, Bf2, acc[2][2], 0, 0, 0); \
    acc[2][3] = __builtin_amdgcn_mfma_f32_16x16x32_bf16(AC2, Bf3, acc[2][3], 0, 0, 0); \
    acc[3][0] = __builtin_amdgcn_mfma_f32_16x16x32_bf16(AC3, Bf0, acc[3][0], 0, 0, 0); \
    acc[3][1] = __builtin_amdgcn_mfma_f32_16x16x32_bf16(AC3, Bf1, acc[3][1], 0, 0, 0); \
    acc[3][2] = __builtin_amdgcn_mfma_f32_16x16x32_bf16(AC3, Bf2, acc[3][2], 0, 0, 0); \
    acc[3][3] = __builtin_amdgcn_mfma_f32_16x16x32_bf16(AC3, Bf3, acc[3][3], 0, 0, 0); \
    __builtin_amdgcn_s_setprio(0);                                                \
} while (0)

__global__ __launch_bounds__(256, 4)
void conv_gemm(const unsigned short* __restrict__ Wg, const unsigned short* __restrict__ Xg,
               const int* __restrict__ lengths, const int* __restrict__ wl,
               const float* __restrict__ cb1, const float* __restrict__ cb2,
               const float* __restrict__ cb3, const float* __restrict__ cb4,
               const float* __restrict__ cb5,
               float* __restrict__ pools) {
    __shared__ __align__(16) char smem[33024];               // max(4x8KB B-ring, Gs)
    unsigned short* ldsB = (unsigned short*)smem;            // 4 x 4096 ushorts
    float* Gs = (float*)smem;                                // 64*129 floats (epilogue)

    int cnt = wl[640];
    // XCD-aligned decode: siblings of one wl-position share g&7 (same XCD
    // under round-robin) and are consecutive within the class.
    int g = blockIdx.x;
    int xcd = g & 7;
    int q = g >> 3;
    int mt = q & 15;
    int wk = (q >> 4) * 8 + xcd;
    if (wk >= cnt) return;
    int item = wl[wk];
    int b = item >> 3, tt = item & 7;
    int n0 = tt * 124 - ((tt >> 2) * 112);   // {0,124,248,372,384}
    int L = lengths[b];
    int Leff = L > 5 ? L : 5;

    int tid = threadIdx.x;
    int wid = tid >> 6, lane = tid & 63;
    int wm = wid >> 1, wn = wid & 1;
    int llo = lane & 15, quad = lane >> 4;
    int psw = quad ^ ((llo >> 1) & 3);   // swizzled physical chunk for B frag reads

    int nb0 = b * 512 + n0;

    v4f acc[4][4];
    #pragma unroll
    for (int i = 0; i < 4; ++i)
        #pragma unroll
        for (int j = 0; j < 4; ++j) acc[i][j] = v4f{0.f, 0.f, 0.f, 0.f};

    // B staging: wave wid covers rows [wid*32, wid*32+32) in 2 insts of 16 rows
    int srow = lane >> 2;                           // 0..15
    int gchunk = (lane & 3) ^ ((lane >> 3) & 3);    // global chunk for physical slot lane&3
    const unsigned short* gB = Xg + (nb0 + wid * 32 + srow) * 512 + gchunk * 8;
    int sdst = (wid * 32) * 32;   // ushort offset of this wave's staging rows

    // A fragment stream: pre-swizzled Wg2, 16B/lane coalesced from L2.
    const unsigned short* pA = Wg + (mt * 2 + wm) * 32768 + lane * 8;

    // prologue: stage B k-tiles 0,1 into ring bufs 0,1; then A(0) frags
    #pragma unroll
    for (int p = 0; p < 2; ++p) {
        #pragma unroll
        for (int q2 = 0; q2 < 2; ++q2) {
            __builtin_amdgcn_global_load_lds(
                (const __attribute__((address_space(1))) unsigned int*)(gB + q2 * (16 * 512) + p * 32),
                (__attribute__((address_space(3))) unsigned int*)&ldsB[p * 4096 + sdst + q2 * 512],
                16, 0, 0);
        }
    }
    v8s AfA0, AfA1, AfA2, AfA3;   // bank A: even kt compute
    v8s AfB0, AfB1, AfB2, AfB3;   // bank B: odd  kt compute
    asm volatile("global_load_dwordx4 %0, %1, off"             : "=v"(AfA0) : "v"(pA) : "memory");
    asm volatile("global_load_dwordx4 %0, %1, off offset:1024" : "=v"(AfA1) : "v"(pA) : "memory");
    asm volatile("global_load_dwordx4 %0, %1, off offset:2048" : "=v"(AfA2) : "v"(pA) : "memory");
    asm volatile("global_load_dwordx4 %0, %1, off offset:3072" : "=v"(AfA3) : "v"(pA) : "memory");
    const unsigned short* pAc = pA + 2048;   // next load = A(1)

    #pragma unroll 1
    for (int t = 0; t < 7; ++t) {
        int kte = 2 * t;
        KT_BODY(kte,     AfA0, AfA1, AfA2, AfA3, AfB0, AfB1, AfB2, AfB3, true, true, "vmcnt(2)");
        KT_BODY(kte + 1, AfB0, AfB1, AfB2, AfB3, AfA0, AfA1, AfA2, AfA3, true, true, "vmcnt(2)");
    }
    // tails: kt=14 (no stage, loads A(15) into bank B), kt=15 (no stage/load)
    KT_BODY(14, AfA0, AfA1, AfA2, AfA3, AfB0, AfB1, AfB2, AfB3, false, true,  "vmcnt(0)");
    KT_BODY(15, AfB0, AfB1, AfB2, AfB3, AfA0, AfA1, AfA2, AfA3, false, false, "vmcnt(0)");

    __syncthreads();   // all waves done with B-ring before Gs overwrites smem

    // ---- epilogue: 2 phases of 64 rows (4 filter groups each) ----
    #pragma unroll
    for (int phase = 0; phase < 2; ++phase) {
        if (wm == phase) {
            // C/D layout: col = lane&15, row = quad*4 + reg  [verified m89/m91]
            #pragma unroll
            for (int mi = 0; mi < 4; ++mi)
                #pragma unroll
                for (int ni = 0; ni < 4; ++ni)
                    #pragma unroll
                    for (int r = 0; r < 4; ++r)
                        Gs[(mi * 16 + quad * 4 + r) * 129 + wn * 64 + ni * 16 + llo] = acc[mi][ni][r];
        }
        __syncthreads();
        // pooling: wave wid handles filter f = mt*8 + phase*4 + wid.
        // Lane owns t = lane and t = lane+64 -> ds_read2 pairs; 5 w-chains
        // reduced with INTERLEAVED butterflies (independent, pipeline).
        {
            int fl = wid;
            int f = mt * 8 + phase * 4 + fl;
            float bias[5] = {cb1[f], cb2[f], cb3[f], cb4[f], cb5[f]};
            const int basew[5] = {0, 1, 3, 6, 10};
            const float* gbase = &Gs[(fl * 16) * 129 + lane];
            float vm[5];
            #pragma unroll
            for (int w = 1; w <= 5; ++w) {
                float s0 = 0.f, s1 = 0.f;
                #pragma unroll
                for (int j = 0; j < w; ++j) {
                    int o = basew[w - 1] * 129 + j * 130;
                    s0 += gbase[o];        // G[row+j][lane+j]
                    s1 += gbase[o + 64];   // G[row+j][lane+64+j]
                }
                int limv = Leff - w + 1 - n0;
                int lim = 128 - w; if (limv - 1 < lim) lim = limv - 1;
                float m = -1.f;
                if (lane <= lim)      m = fmaxf(m, fmaxf(s0 + bias[w - 1], 0.f));
                if (lane + 64 <= lim) m = fmaxf(m, fmaxf(s1 + bias[w - 1], 0.f));
                vm[w - 1] = m;
            }
            #pragma unroll
            for (int off = 32; off >= 1; off >>= 1) {
                #pragma unroll
                for (int w = 0; w < 5; ++w)
                    vm[w] = fmaxf(vm[w], __shfl_xor(vm[w], off));
            }
            if (lane == 0 && vm[0] >= 0.f) atomicMax((int*)&pools[(b * 5 + 0) * NFC + f], __float_as_int(vm[0]));
            if (lane == 1 && vm[1] >= 0.f) atomicMax((int*)&pools[(b * 5 + 1) * NFC + f], __float_as_int(vm[1]));
            if (lane == 2 && vm[2] >= 0.f) atomicMax((int*)&pools[(b * 5 + 2) * NFC + f], __float_as_int(vm[2]));
            if (lane == 3 && vm[3] >= 0.f) atomicMax((int*)&pools[(b * 5 + 3) * NFC + f], __float_as_int(vm[3]));
            if (lane == 4 && vm[4] >= 0.f) atomicMax((int*)&pools[(b * 5 + 4) * NFC + f], __float_as_int(vm[4]));
        }
        __syncthreads();
    }
}

// ---------------------------------------------------------------------------
// Kernel 2: per-batch dot(feat, v) + c -> sigmoid.  (unchanged)
// ---------------------------------------------------------------------------
__global__ void head(const float* __restrict__ pools, const float* __restrict__ v,
                     float* __restrict__ out) {
    int b = blockIdx.x;
    int tid = threadIdx.x;
    float s = 0.f;
    for (int k = tid; k < 640; k += 256) s += pools[b * 640 + k] * v[k];
    __shared__ float red[256];
    red[tid] = s;
    __syncthreads();
    for (int st = 128; st; st >>= 1) {
        if (tid < st) red[tid] += red[tid + st];
        __syncthreads();
    }
    if (tid == 0) out[b] = 1.f / (1.f + expf(-(red[0] + v[640])));
}

// ---------------------------------------------------------------------------
extern "C" void kernel_launch(void* const* d_in, const int* in_sizes, int n_in,
                              void* d_out, int out_size, void* d_ws, size_t ws_size,
                              hipStream_t stream) {
    const float* enc  = (const float*)d_in[0];
    const int* lens   = (const int*)d_in[1];
    const float* w1   = (const float*)d_in[2];
    const float* b1   = (const float*)d_in[3];
    const float* w2   = (const float*)d_in[4];
    const float* b2   = (const float*)d_in[5];
    const float* w3   = (const float*)d_in[6];
    const float* b3   = (const float*)d_in[7];
    const float* w4   = (const float*)d_in[8];
    const float* b4   = (const float*)d_in[9];
    const float* w5   = (const float*)d_in[10];
    const float* b5   = (const float*)d_in[11];
    const float* fc1w = (const float*)d_in[12];
    const float* fc1b = (const float*)d_in[13];
    const float* fc2w = (const float*)d_in[14];
    const float* fc2b = (const float*)d_in[15];
    float* out = (float*)d_out;

    // workspace layout
    unsigned short* Xg = (unsigned short*)d_ws;          // 33,554,432 ushorts (64 MB)
    unsigned short* Wg = Xg + 33554432;                  // 1,048,576 ushorts (2 MB, frag-order)
    float* pools  = (float*)(Wg + 1048576);              // 81,920 floats
    float* vbuf   = pools + 81920;                       // 641 floats
    int* wlist    = (int*)(vbuf + 641);                  // 641 ints

    prep_all<<<12610, 256, 0, stream>>>(enc, lens, Xg, w1, w2, w3, w4, w5, Wg, pools,
                                        fc1w, fc1b, fc2w, fc2b, vbuf, wlist);
    conv_gemm<<<10240, 256, 0, stream>>>(Wg, Xg, lens, wlist, b1, b2, b3, b4, b5, pools);
    head<<<128, 256, 0, stream>>>(pools, vbuf, out);
}